// Round 4
// baseline (350.175 us; speedup 1.0000x reference)
//
#include <hip/hip_runtime.h>
#include <hip/hip_fp16.h>

#define SPATIAL_SCALE 0.25f
#define PH_ 7
#define PW_ 7
#define NBINS 49
#define NSAMP 196          // 49 bins * 4 samples
#define C_ 256
#define H_ 256
#define W_ 256
#define HW_ (H_ * W_)

// ---------------------------------------------------------------------------
// Transpose NCHW fp32 -> NHWC fp16. 64px x 64ch tile through LDS (fp32 tile,
// convert at write-out). Both global sides fully coalesced, all lines fully
// covered.
// ---------------------------------------------------------------------------
struct H4 { __half2 a, b; };   // 8 bytes = 4 channels fp16

__global__ __launch_bounds__(256) void transpose_nchw_nhwc_h(
    const float* __restrict__ in, __half* __restrict__ out) {
  __shared__ float tile[64 * 68];     // [pixel][channel], stride 68
  const int b  = blockIdx.z;
  const int p0 = blockIdx.x * 64;
  const int c0 = blockIdx.y * 64;
  const int t  = threadIdx.x;
  const int i  = t & 15;              // pixel quad index   (x4)
  const int q  = t >> 4;              // channel quad index (x4), 0..15

  const float* src = in + (size_t)b * C_ * HW_ + (size_t)(c0 + 4 * q) * HW_
                        + (p0 + 4 * i);
  const float4 r0 = *(const float4*)(src + 0 * HW_);
  const float4 r1 = *(const float4*)(src + 1 * HW_);
  const float4 r2 = *(const float4*)(src + 2 * HW_);
  const float4 r3 = *(const float4*)(src + 3 * HW_);

  float* tp = &tile[(4 * i) * 68 + 4 * q];
  *(float4*)(tp + 0 * 68) = make_float4(r0.x, r1.x, r2.x, r3.x);
  *(float4*)(tp + 1 * 68) = make_float4(r0.y, r1.y, r2.y, r3.y);
  *(float4*)(tp + 2 * 68) = make_float4(r0.z, r1.z, r2.z, r3.z);
  *(float4*)(tp + 3 * 68) = make_float4(r0.w, r1.w, r2.w, r3.w);
  __syncthreads();

  __half* dst = out + (size_t)b * HW_ * C_ + (size_t)(p0 + q) * C_ + (c0 + 4 * i);
#pragma unroll
  for (int k = 0; k < 4; ++k) {
    const float4 v = *(const float4*)&tile[(16 * k + q) * 68 + 4 * i];
    H4 h;
    h.a = __floats2half2_rn(v.x, v.y);
    h.b = __floats2half2_rn(v.z, v.w);
    *(H4*)(dst + (size_t)(16 * k) * C_) = h;   // 8B store, 8B-aligned
  }
}

// ---------------------------------------------------------------------------
// Main kernel (fp16 NHWC): one block per roi, 4 waves.
// thread t: channel pair c2 = t&127 (channels 2c2, 2c2+1), bin half = t>>7.
// Register float2 accumulator per bin, direct dword stores (runs merge in L2).
// LDS = descriptors only (3.9 KB) -> occupancy capped by grid (4 blocks/CU).
// ---------------------------------------------------------------------------
__global__ __launch_bounds__(256, 4) void roi_align_rotated_nhwc_h(
    const __half* __restrict__ feat, const float* __restrict__ rois,
    float* __restrict__ out) {
  __shared__ int    d_off[NSAMP];     // corner base offset | dx(1) | dy(2)
  __shared__ float4 d_wt[NSAMP];      // w11,w12,w21,w22 (fp32)

  const int r = blockIdx.x;
  const int t = threadIdx.x;

  if (t < NSAMP) {
    const float* rp = rois + r * 6;
    const int   b  = (int)rp[0];
    const float cx = rp[1] * SPATIAL_SCALE - 0.5f;
    const float cy = rp[2] * SPATIAL_SCALE - 0.5f;
    const float rw = rp[3] * SPATIAL_SCALE;
    const float rh = rp[4] * SPATIAL_SCALE;
    float sn, cs;
    sincosf(rp[5], &sn, &cs);         // CLOCKWISE=False
    const float bin_h = rh / (float)PH_;
    const float bin_w = rw / (float)PW_;

    const int bin = t >> 2;
    const int sub = t & 3;
    const int ph  = bin / 7;
    const int pw  = bin - ph * 7;
    const int iy  = sub >> 1;
    const int ix  = sub & 1;

    const float yy = -0.5f * rh + ((float)ph + ((float)iy + 0.5f) * 0.5f) * bin_h;
    const float xx = -0.5f * rw + ((float)pw + ((float)ix + 0.5f) * 0.5f) * bin_w;
    float y = yy * cs - xx * sn + cy;
    float x = yy * sn + xx * cs + cx;

    const bool valid = (y > -1.0f) && (y < (float)H_) &&
                       (x > -1.0f) && (x < (float)W_);
    y = fminf(fmaxf(y, 0.0f), (float)(H_ - 1));
    x = fminf(fmaxf(x, 0.0f), (float)(W_ - 1));
    const int yl = (int)y;
    const int xl = (int)x;
    const float ly = y - (float)yl, lx = x - (float)xl;
    const float hy = 1.0f - ly, hx = 1.0f - lx;
    float w11 = hy * hx, w12 = hy * lx, w21 = ly * hx, w22 = ly * lx;
    if (!valid) { w11 = w12 = w21 = w22 = 0.0f; }

    const int base = ((b * H_ + yl) * W_ + xl) * C_;   // multiple of 256
    const int dxf  = (xl < W_ - 1) ? 1 : 0;
    const int dyf  = (yl < H_ - 1) ? 2 : 0;
    d_off[t] = base | dxf | dyf;
    d_wt[t]  = make_float4(w11, w12, w21, w22);
  }
  __syncthreads();

  const int c2   = t & 127;           // channel pair index
  const int bh   = t >> 7;            // bin-half selector
  const int bin0 = bh ? 25 : 0;
  const int bin1 = bh ? 49 : 25;
  const int cb   = 2 * c2;            // channel base
  float* outr = out + (size_t)r * (C_ * NBINS) + (size_t)cb * NBINS;

  for (int bin = bin0; bin < bin1; ++bin) {
    float accx = 0.0f, accy = 0.0f;
#pragma unroll
    for (int sub = 0; sub < 4; ++sub) {
      const int s  = bin * 4 + sub;
      const int pc = d_off[s];
      const float4 wt = d_wt[s];
      const int base = (pc & ~255) + cb;
      const int dx   = (pc & 1) ? C_ : 0;
      const int dy   = (pc & 2) ? (W_ * C_) : 0;
      const float2 f00 = __half22float2(*(const __half2*)(feat + base));
      const float2 f01 = __half22float2(*(const __half2*)(feat + base + dx));
      const float2 f10 = __half22float2(*(const __half2*)(feat + base + dy));
      const float2 f11 = __half22float2(*(const __half2*)(feat + base + dx + dy));
      accx += wt.x * f00.x + wt.y * f01.x + wt.z * f10.x + wt.w * f11.x;
      accy += wt.x * f00.y + wt.y * f01.y + wt.z * f10.y + wt.w * f11.y;
    }
    outr[bin]         = accx * 0.25f;
    outr[NBINS + bin] = accy * 0.25f;
  }
}

// ---------------------------------------------------------------------------
// Fallback: direct NCHW fp32 (only if ws too small for the transposed copy).
// ---------------------------------------------------------------------------
__global__ __launch_bounds__(256) void roi_align_rotated_nchw(
    const float* __restrict__ feat, const float* __restrict__ rois,
    float* __restrict__ out) {
  __shared__ int    d_pix[NSAMP];
  __shared__ int    d_step[NSAMP];
  __shared__ float4 d_wt[NSAMP];
  __shared__ float  res[NBINS * 257];

  const int r = blockIdx.x;
  const int t = threadIdx.x;
  if (t < NSAMP) {
    const float* rp = rois + r * 6;
    const int   b  = (int)rp[0];
    const float cx = rp[1] * SPATIAL_SCALE - 0.5f;
    const float cy = rp[2] * SPATIAL_SCALE - 0.5f;
    const float rw = rp[3] * SPATIAL_SCALE;
    const float rh = rp[4] * SPATIAL_SCALE;
    float sn, cs;
    sincosf(rp[5], &sn, &cs);
    const float bin_h = rh / (float)PH_;
    const float bin_w = rw / (float)PW_;
    const int bin = t >> 2, sub = t & 3;
    const int ph = bin / 7, pw = bin - ph * 7;
    const int iy = sub >> 1, ix = sub & 1;
    const float yy = -0.5f * rh + ((float)ph + ((float)iy + 0.5f) * 0.5f) * bin_h;
    const float xx = -0.5f * rw + ((float)pw + ((float)ix + 0.5f) * 0.5f) * bin_w;
    float y = yy * cs - xx * sn + cy;
    float x = yy * sn + xx * cs + cx;
    const bool valid = (y > -1.0f) && (y < (float)H_) &&
                       (x > -1.0f) && (x < (float)W_);
    y = fminf(fmaxf(y, 0.0f), (float)(H_ - 1));
    x = fminf(fmaxf(x, 0.0f), (float)(W_ - 1));
    const int yl = (int)y, xl = (int)x;
    const float ly = y - (float)yl, lx = x - (float)xl;
    const float hy = 1.0f - ly, hx = 1.0f - lx;
    float w11 = hy * hx, w12 = hy * lx, w21 = ly * hx, w22 = ly * lx;
    if (!valid) { w11 = w12 = w21 = w22 = 0.0f; }
    d_pix[t]  = (b * H_ + yl) * W_ + xl;
    d_step[t] = ((xl < W_ - 1) ? 1 : 0) | ((yl < H_ - 1) ? 2 : 0);
    d_wt[t]   = make_float4(w11, w12, w21, w22);
  }
  __syncthreads();

  const int c = t;
  const size_t coff = (size_t)c * HW_;
  for (int bin = 0; bin < NBINS; ++bin) {
    float acc = 0.0f;
#pragma unroll
    for (int sub = 0; sub < 4; ++sub) {
      const int s = bin * 4 + sub;
      const int p = d_pix[s];
      const int st = d_step[s];
      const int dx = (st & 1) ? 1 : 0;
      const int dy = (st & 2) ? W_ : 0;
      const float4 w = d_wt[s];
      const int bb = (p / HW_) * C_ * HW_ + (p % HW_);
      acc += w.x * feat[bb + coff];
      acc += w.y * feat[bb + coff + dx];
      acc += w.z * feat[bb + coff + dy];
      acc += w.w * feat[bb + coff + dx + dy];
    }
    res[bin * 257 + c] = acc * 0.25f;
  }
  __syncthreads();
  float* outr = out + (size_t)r * (C_ * NBINS);
#pragma unroll 1
  for (int i = t; i < C_ * NBINS; i += 256) {
    const int cc = i / NBINS;
    const int bb = i - cc * NBINS;
    outr[i] = res[bb * 257 + cc];
  }
}

// ---------------------------------------------------------------------------
extern "C" void kernel_launch(void* const* d_in, const int* in_sizes, int n_in,
                              void* d_out, int out_size, void* d_ws, size_t ws_size,
                              hipStream_t stream) {
  const float* feat = (const float*)d_in[0];
  const float* rois = (const float*)d_in[1];
  float* out = (float*)d_out;
  const int n_rois  = in_sizes[1] / 6;
  const int n_batch = in_sizes[0] / (C_ * HW_);

  const size_t need = (size_t)n_batch * C_ * HW_ * sizeof(__half);
  if (ws_size >= need) {
    __half* feat_h = (__half*)d_ws;
    dim3 tg(HW_ / 64, C_ / 64, n_batch);
    hipLaunchKernelGGL(transpose_nchw_nhwc_h, tg, dim3(256), 0, stream, feat, feat_h);
    hipLaunchKernelGGL(roi_align_rotated_nhwc_h, dim3(n_rois), dim3(256),
                       0, stream, feat_h, rois, out);
  } else {
    hipLaunchKernelGGL(roi_align_rotated_nchw, dim3(n_rois), dim3(256),
                       0, stream, feat, rois, out);
  }
}

// Round 5
// 264.961 us; speedup vs baseline: 1.3216x; 1.3216x over previous
//
#include <hip/hip_runtime.h>
#include <hip/hip_fp16.h>

#define SPATIAL_SCALE 0.25f
#define PH_ 7
#define PW_ 7
#define NBINS 49
#define NSAMP 196          // 49 bins * 4 samples
#define C_ 256
#define H_ 256
#define W_ 256
#define HW_ (H_ * W_)

// ---------------------------------------------------------------------------
// Transpose NCHW fp32 -> NHWC fp16. 64px x 64ch tile through LDS (fp32 tile,
// convert at write-out). Both global sides fully coalesced, full-line covered.
// ---------------------------------------------------------------------------
struct H4 { __half2 a, b; };   // 8 bytes = 4 channels fp16

__global__ __launch_bounds__(256) void transpose_nchw_nhwc_h(
    const float* __restrict__ in, __half* __restrict__ out) {
  __shared__ float tile[64 * 68];     // [pixel][channel], stride 68
  const int b  = blockIdx.z;
  const int p0 = blockIdx.x * 64;
  const int c0 = blockIdx.y * 64;
  const int t  = threadIdx.x;
  const int i  = t & 15;              // pixel quad index   (x4)
  const int q  = t >> 4;              // channel quad index (x4), 0..15

  const float* src = in + (size_t)b * C_ * HW_ + (size_t)(c0 + 4 * q) * HW_
                        + (p0 + 4 * i);
  const float4 r0 = *(const float4*)(src + 0 * HW_);
  const float4 r1 = *(const float4*)(src + 1 * HW_);
  const float4 r2 = *(const float4*)(src + 2 * HW_);
  const float4 r3 = *(const float4*)(src + 3 * HW_);

  float* tp = &tile[(4 * i) * 68 + 4 * q];
  *(float4*)(tp + 0 * 68) = make_float4(r0.x, r1.x, r2.x, r3.x);
  *(float4*)(tp + 1 * 68) = make_float4(r0.y, r1.y, r2.y, r3.y);
  *(float4*)(tp + 2 * 68) = make_float4(r0.z, r1.z, r2.z, r3.z);
  *(float4*)(tp + 3 * 68) = make_float4(r0.w, r1.w, r2.w, r3.w);
  __syncthreads();

  __half* dst = out + (size_t)b * HW_ * C_ + (size_t)(p0 + q) * C_ + (c0 + 4 * i);
#pragma unroll
  for (int k = 0; k < 4; ++k) {
    const float4 v = *(const float4*)&tile[(16 * k + q) * 68 + 4 * i];
    H4 h;
    h.a = __floats2half2_rn(v.x, v.y);
    h.b = __floats2half2_rn(v.z, v.w);
    *(H4*)(dst + (size_t)(16 * k) * C_) = h;   // 8B store, 8B-aligned
  }
}

// ---------------------------------------------------------------------------
// Main kernel (fp16 NHWC): one block per roi, 4 waves.
// Processes channels in two halves of 128. Within a half: wave w handles
// bins w, w+4, ...; lanes cover the 128 channels as half2 (256 B per wave
// load instruction). Results staged in res[49][128] (XOR-swizzled pair
// columns), then written as one contiguous 25 KB run per half -> linear
// full-line HBM writes (proven 50 MB total in R1/R3).
// LDS ~29 KB -> occupancy capped by grid (4 blocks/CU).
// ---------------------------------------------------------------------------
__global__ __launch_bounds__(256, 4) void roi_align_rotated_nhwc_h(
    const __half* __restrict__ feat, const float* __restrict__ rois,
    float* __restrict__ out) {
  __shared__ int    d_off[NSAMP];     // corner base offset | dx(1) | dy(2)
  __shared__ float4 d_wt[NSAMP];      // w11,w12,w21,w22 (fp32)
  __shared__ float  res[NBINS * 128]; // one channel-half, swizzled pairs

  const int r = blockIdx.x;
  const int t = threadIdx.x;

  if (t < NSAMP) {
    const float* rp = rois + r * 6;
    const int   b  = (int)rp[0];
    const float cx = rp[1] * SPATIAL_SCALE - 0.5f;
    const float cy = rp[2] * SPATIAL_SCALE - 0.5f;
    const float rw = rp[3] * SPATIAL_SCALE;
    const float rh = rp[4] * SPATIAL_SCALE;
    float sn, cs;
    sincosf(rp[5], &sn, &cs);         // CLOCKWISE=False
    const float bin_h = rh / (float)PH_;
    const float bin_w = rw / (float)PW_;

    const int bin = t >> 2;
    const int sub = t & 3;
    const int ph  = bin / 7;
    const int pw  = bin - ph * 7;
    const int iy  = sub >> 1;
    const int ix  = sub & 1;

    const float yy = -0.5f * rh + ((float)ph + ((float)iy + 0.5f) * 0.5f) * bin_h;
    const float xx = -0.5f * rw + ((float)pw + ((float)ix + 0.5f) * 0.5f) * bin_w;
    float y = yy * cs - xx * sn + cy;
    float x = yy * sn + xx * cs + cx;

    const bool valid = (y > -1.0f) && (y < (float)H_) &&
                       (x > -1.0f) && (x < (float)W_);
    y = fminf(fmaxf(y, 0.0f), (float)(H_ - 1));
    x = fminf(fmaxf(x, 0.0f), (float)(W_ - 1));
    const int yl = (int)y;
    const int xl = (int)x;
    const float ly = y - (float)yl, lx = x - (float)xl;
    const float hy = 1.0f - ly, hx = 1.0f - lx;
    float w11 = hy * hx, w12 = hy * lx, w21 = ly * hx, w22 = ly * lx;
    if (!valid) { w11 = w12 = w21 = w22 = 0.0f; }

    const int base = ((b * H_ + yl) * W_ + xl) * C_;   // multiple of 256
    const int dxf  = (xl < W_ - 1) ? 1 : 0;
    const int dyf  = (yl < H_ - 1) ? 2 : 0;
    d_off[t] = base | dxf | dyf;
    d_wt[t]  = make_float4(w11, w12, w21, w22);
  }
  __syncthreads();

  const int w    = t >> 6;            // wave id 0..3
  const int lane = t & 63;
  const int cp   = 2 * lane;          // channel-pair base within half (even)
  float* outr = out + (size_t)r * (C_ * NBINS);

#pragma unroll 1
  for (int h = 0; h < 2; ++h) {
    const int ch0 = 128 * h;
    for (int bin = w; bin < NBINS; bin += 4) {
      float accx = 0.0f, accy = 0.0f;
#pragma unroll
      for (int sub = 0; sub < 4; ++sub) {
        const int s  = bin * 4 + sub;
        const int pc = d_off[s];
        const float4 wt = d_wt[s];
        const int base = (pc & ~255) + ch0 + cp;
        const int dx   = (pc & 1) ? C_ : 0;
        const int dy   = (pc & 2) ? (W_ * C_) : 0;
        const float2 f00 = __half22float2(*(const __half2*)(feat + base));
        const float2 f01 = __half22float2(*(const __half2*)(feat + base + dx));
        const float2 f10 = __half22float2(*(const __half2*)(feat + base + dy));
        const float2 f11 = __half22float2(*(const __half2*)(feat + base + dx + dy));
        accx += wt.x * f00.x + wt.y * f01.x + wt.z * f10.x + wt.w * f11.x;
        accy += wt.x * f00.y + wt.y * f01.y + wt.z * f10.y + wt.w * f11.y;
      }
      const int sc = cp ^ ((bin & 31) << 1);   // swizzled even column
      *(float2*)&res[bin * 128 + sc] = make_float2(accx * 0.25f, accy * 0.25f);
    }
    __syncthreads();
    // contiguous 128*49-float run for this channel half
#pragma unroll 1
    for (int i = t; i < 128 * NBINS; i += 256) {
      const int cc  = i / NBINS;       // channel within half
      const int bb  = i - cc * NBINS;  // bin
      const int col = ((cc & ~1) ^ ((bb & 31) << 1)) | (cc & 1);
      outr[(size_t)ch0 * NBINS + i] = res[bb * 128 + col];
    }
    __syncthreads();
  }
}

// ---------------------------------------------------------------------------
// Fallback: direct NCHW fp32 (only if ws too small for the transposed copy).
// ---------------------------------------------------------------------------
__global__ __launch_bounds__(256) void roi_align_rotated_nchw(
    const float* __restrict__ feat, const float* __restrict__ rois,
    float* __restrict__ out) {
  __shared__ int    d_pix[NSAMP];
  __shared__ int    d_step[NSAMP];
  __shared__ float4 d_wt[NSAMP];
  __shared__ float  res[NBINS * 257];

  const int r = blockIdx.x;
  const int t = threadIdx.x;
  if (t < NSAMP) {
    const float* rp = rois + r * 6;
    const int   b  = (int)rp[0];
    const float cx = rp[1] * SPATIAL_SCALE - 0.5f;
    const float cy = rp[2] * SPATIAL_SCALE - 0.5f;
    const float rw = rp[3] * SPATIAL_SCALE;
    const float rh = rp[4] * SPATIAL_SCALE;
    float sn, cs;
    sincosf(rp[5], &sn, &cs);
    const float bin_h = rh / (float)PH_;
    const float bin_w = rw / (float)PW_;
    const int bin = t >> 2, sub = t & 3;
    const int ph = bin / 7, pw = bin - ph * 7;
    const int iy = sub >> 1, ix = sub & 1;
    const float yy = -0.5f * rh + ((float)ph + ((float)iy + 0.5f) * 0.5f) * bin_h;
    const float xx = -0.5f * rw + ((float)pw + ((float)ix + 0.5f) * 0.5f) * bin_w;
    float y = yy * cs - xx * sn + cy;
    float x = yy * sn + xx * cs + cx;
    const bool valid = (y > -1.0f) && (y < (float)H_) &&
                       (x > -1.0f) && (x < (float)W_);
    y = fminf(fmaxf(y, 0.0f), (float)(H_ - 1));
    x = fminf(fmaxf(x, 0.0f), (float)(W_ - 1));
    const int yl = (int)y, xl = (int)x;
    const float ly = y - (float)yl, lx = x - (float)xl;
    const float hy = 1.0f - ly, hx = 1.0f - lx;
    float w11 = hy * hx, w12 = hy * lx, w21 = ly * hx, w22 = ly * lx;
    if (!valid) { w11 = w12 = w21 = w22 = 0.0f; }
    d_pix[t]  = (b * H_ + yl) * W_ + xl;
    d_step[t] = ((xl < W_ - 1) ? 1 : 0) | ((yl < H_ - 1) ? 2 : 0);
    d_wt[t]   = make_float4(w11, w12, w21, w22);
  }
  __syncthreads();

  const int c = t;
  const size_t coff = (size_t)c * HW_;
  for (int bin = 0; bin < NBINS; ++bin) {
    float acc = 0.0f;
#pragma unroll
    for (int sub = 0; sub < 4; ++sub) {
      const int s = bin * 4 + sub;
      const int p = d_pix[s];
      const int st = d_step[s];
      const int dx = (st & 1) ? 1 : 0;
      const int dy = (st & 2) ? W_ : 0;
      const float4 w = d_wt[s];
      const int bb = (p / HW_) * C_ * HW_ + (p % HW_);
      acc += w.x * feat[bb + coff];
      acc += w.y * feat[bb + coff + dx];
      acc += w.z * feat[bb + coff + dy];
      acc += w.w * feat[bb + coff + dx + dy];
    }
    res[bin * 257 + c] = acc * 0.25f;
  }
  __syncthreads();
  float* outr = out + (size_t)r * (C_ * NBINS);
#pragma unroll 1
  for (int i = t; i < C_ * NBINS; i += 256) {
    const int cc = i / NBINS;
    const int bb = i - cc * NBINS;
    outr[i] = res[bb * 257 + cc];
  }
}

// ---------------------------------------------------------------------------
extern "C" void kernel_launch(void* const* d_in, const int* in_sizes, int n_in,
                              void* d_out, int out_size, void* d_ws, size_t ws_size,
                              hipStream_t stream) {
  const float* feat = (const float*)d_in[0];
  const float* rois = (const float*)d_in[1];
  float* out = (float*)d_out;
  const int n_rois  = in_sizes[1] / 6;
  const int n_batch = in_sizes[0] / (C_ * HW_);

  const size_t need = (size_t)n_batch * C_ * HW_ * sizeof(__half);
  if (ws_size >= need) {
    __half* feat_h = (__half*)d_ws;
    dim3 tg(HW_ / 64, C_ / 64, n_batch);
    hipLaunchKernelGGL(transpose_nchw_nhwc_h, tg, dim3(256), 0, stream, feat, feat_h);
    hipLaunchKernelGGL(roi_align_rotated_nhwc_h, dim3(n_rois), dim3(256),
                       0, stream, feat_h, rois, out);
  } else {
    hipLaunchKernelGGL(roi_align_rotated_nchw, dim3(n_rois), dim3(256),
                       0, stream, feat, rois, out);
  }
}